// Round 2
// baseline (125.609 us; speedup 1.0000x reference)
//
#include <hip/hip_runtime.h>

#define IMH 512
#define IMW 512
#define TW 32
#define TH 16
#define HW_ (TW + 2)           // 34
#define HH_ (TH + 2)           // 18
#define NHALO (HW_ * HH_)      // 612
#define NTHR 512

// Per halo pixel: 32-float row = 8 float4 chunks, XOR-swizzled: logical chunk k
// of pixel p lives at physical slot (k+p)&7. Channels: c=0..2 -> Z, c=3+ij*3+s
// -> w_pre, c=30,31 pad. Raw w_k staged into chunks 0..6 (27 floats) first,
// transformed in place (each pixel row touched only by its owner thread).
__global__ __launch_bounds__(NTHR, 4)
void hmm_fused(const float* __restrict__ obs,
               const float* __restrict__ P,       // P[o*3+s]
               const float* __restrict__ u_k,
               const float* __restrict__ w_k,     // pix*27 + s*9 + i*3 + j
               const float* __restrict__ conv_w,  // (S_out,S_in,3,3)
               const float* __restrict__ conv_b,
               float* __restrict__ out) {
    __shared__ float4 lds4[NHALO * 8];             // 78,336 B -> 2 blocks/CU
    float* lds = (float*)lds4;

    const int tid = threadIdx.x;
    const int w0 = blockIdx.x * TW;
    const int h0 = blockIdx.y * TH;

    float Pm[9];
#pragma unroll
    for (int i = 0; i < 9; ++i) Pm[i] = P[i];

    // ---- Stage 0: coalesced staging of w_k halo rows into swizzled LDS chunks
    for (int r = 0; r < HH_; ++r) {
        const int hh = h0 + r - 1;
        if (hh < 0 || hh >= IMH) continue;
        const long long gbase = ((long long)hh * IMW + (w0 - 1)) * 27;
        for (int f = tid; f < HW_ * 27; f += NTHR) {   // 918 floats/row, coalesced
            const int p = f / 27;
            const int c = f - p * 27;
            const int ww = w0 - 1 + p;
            float v = 0.0f;
            if (ww >= 0 && ww < IMW) v = w_k[gbase + f];
            const int pr = r * HW_ + p;
            lds[pr * 32 + (((c >> 2) + pr) & 7) * 4 + (c & 3)] = v;
        }
    }

    // conv weights/bias: wave-uniform -> SGPRs
    float cw[81];
#pragma unroll
    for (int i = 0; i < 81; ++i) cw[i] = conv_w[i];
    const float cb0 = conv_b[0], cb1 = conv_b[1], cb2 = conv_b[2];

    __syncthreads();

    // ---- Stage A: in-place transform raw w_k (+obs,u_k) -> Z, w_pre
    for (int p = tid; p < NHALO; p += NTHR) {
        const int rr = p / HW_;
        const int cc = p - rr * HW_;
        const int hh = h0 + rr - 1;
        const int ww = w0 + cc - 1;
        float4 o[8];
        if ((unsigned)hh < IMH && (unsigned)ww < IMW) {
            float wv[28];
#pragma unroll
            for (int k = 0; k < 7; ++k) {
                const float4 v = lds4[p * 8 + ((k + p) & 7)];
                wv[4 * k + 0] = v.x; wv[4 * k + 1] = v.y;
                wv[4 * k + 2] = v.z; wv[4 * k + 3] = v.w;
            }
            const int pix = hh * IMW + ww;
            const float ov0 = obs[pix * 3 + 0], ov1 = obs[pix * 3 + 1], ov2 = obs[pix * 3 + 2];
            const float us[3] = {u_k[pix * 3 + 0], u_k[pix * 3 + 1], u_k[pix * 3 + 2]};

            float b[3], Bu[3], bu = 0.0f;
#pragma unroll
            for (int s = 0; s < 3; ++s) {
                b[s] = Pm[0 * 3 + s] * ov0 + Pm[1 * 3 + s] * ov1 + Pm[2 * 3 + s] * ov2;
                Bu[s] = b[s] * us[s];
                bu += Bu[s];
            }
            const float inv_bu = 1.0f / bu;
            float Z[3], oc[32];
#pragma unroll
            for (int s = 0; s < 3; ++s) { Z[s] = Bu[s] * inv_bu; oc[s] = Z[s]; }

            const float ovv[3] = {ov0, ov1, ov2};
#pragma unroll
            for (int i = 0; i < 3; ++i) {
#pragma unroll
                for (int j = 0; j < 3; ++j) {
                    const int ij = i * 3 + j;
                    float du[3], sdu = 0.0f;
#pragma unroll
                    for (int s = 0; s < 3; ++s) {
                        float d = b[s] * wv[s * 9 + ij];
                        if (s == j) d += ovv[i] * us[s];
                        du[s] = d;
                        sdu += d;
                    }
#pragma unroll
                    for (int s = 0; s < 3; ++s)
                        oc[3 + ij * 3 + s] = (du[s] - sdu * Z[s]) * inv_bu;
                }
            }
            oc[30] = 0.0f; oc[31] = 0.0f;
#pragma unroll
            for (int k = 0; k < 8; ++k)
                o[k] = make_float4(oc[4 * k + 0], oc[4 * k + 1], oc[4 * k + 2], oc[4 * k + 3]);
        } else {
#pragma unroll
            for (int k = 0; k < 8; ++k) o[k] = make_float4(0.f, 0.f, 0.f, 0.f);
        }
#pragma unroll
        for (int k = 0; k < 8; ++k) lds4[p * 8 + ((k + p) & 7)] = o[k];
    }

    __syncthreads();

    // ---- Stage B: 3x3 conv over 10 groups via swizzled b128 reads
    const int tx = tid & (TW - 1);
    const int ty = tid >> 5;
    const int hp = (ty + 1) * HW_ + tx + 1;

    float acc[30];
#pragma unroll
    for (int i = 0; i < 30; ++i) acc[i] = 0.0f;

#pragma unroll
    for (int ky = 0; ky < 3; ++ky) {
#pragma unroll
        for (int kx = 0; kx < 3; ++kx) {
            const int tap = ky * 3 + kx;
            const int pn = hp + (ky - 1) * HW_ + (kx - 1);
#pragma unroll
            for (int k = 0; k < 8; ++k) {
                const float4 v4 = lds4[pn * 8 + ((k + pn) & 7)];
                const float cv[4] = {v4.x, v4.y, v4.z, v4.w};
#pragma unroll
                for (int j = 0; j < 4; ++j) {
                    const int c = 4 * k + j;
                    if (c < 30) {
                        const int g = c / 3, si = c - (c / 3) * 3;
                        acc[g * 3 + 0] += cw[0 * 27 + si * 9 + tap] * cv[j];
                        acc[g * 3 + 1] += cw[1 * 27 + si * 9 + tap] * cv[j];
                        acc[g * 3 + 2] += cw[2 * 27 + si * 9 + tap] * cv[j];
                    }
                }
            }
        }
    }

    // softmax (group 0)
    const float y0 = acc[0] + cb0, y1 = acc[1] + cb1, y2 = acc[2] + cb2;
    const float m = fmaxf(y0, fmaxf(y1, y2));
    const float e0 = __expf(y0 - m), e1 = __expf(y1 - m), e2 = __expf(y2 - m);
    const float inv = 1.0f / (e0 + e1 + e2);
    const float p0 = e0 * inv, p1 = e1 * inv, p2 = e2 * inv;

    const int pix = (h0 + ty) * IMW + (w0 + tx);
    out[pix * 3 + 0] = p0; out[pix * 3 + 1] = p1; out[pix * 3 + 2] = p2;

    // softmax JVP per tangent group
    float wout[27];
#pragma unroll
    for (int g = 1; g < 10; ++g) {
        const float a0 = acc[g * 3 + 0], a1 = acc[g * 3 + 1], a2 = acc[g * 3 + 2];
        const float dot = p0 * a0 + p1 * a1 + p2 * a2;
        const int ij = g - 1;
        wout[0 * 9 + ij] = p0 * (a0 - dot);
        wout[1 * 9 + ij] = p1 * (a1 - dot);
        wout[2 * 9 + ij] = p2 * (a2 - dot);
    }

    __syncthreads();   // all stage-B LDS reads done; reuse LDS for output staging

    // stage w-output: lds flat idx == tile-local output idx (ty*864 + tx*27 + c)
#pragma unroll
    for (int c = 0; c < 27; ++c) lds[tid * 27 + c] = wout[c];
    __syncthreads();

    float* outw = out + IMH * IMW * 3;
    for (int idx = tid; idx < TW * TH * 27 / 4; idx += NTHR) {  // 3456 float4
        const int r = idx / 216;
        const int q = idx - r * 216;
        const float4 v = lds4[r * 216 + q];
        float4* dst = (float4*)(outw + ((size_t)(h0 + r) * IMW + w0) * 27);
        dst[q] = v;
    }
}

extern "C" void kernel_launch(void* const* d_in, const int* in_sizes, int n_in,
                              void* d_out, int out_size, void* d_ws, size_t ws_size,
                              hipStream_t stream) {
    const float* obs    = (const float*)d_in[0];
    const float* P      = (const float*)d_in[1];
    const float* u_k    = (const float*)d_in[2];
    const float* w_k    = (const float*)d_in[3];
    const float* conv_w = (const float*)d_in[4];
    const float* conv_b = (const float*)d_in[5];
    float* out = (float*)d_out;

    dim3 grid(IMW / TW, IMH / TH);   // (16, 32) = 512 blocks = 2/CU
    hmm_fused<<<grid, NTHR, 0, stream>>>(obs, P, u_k, w_k, conv_w, conv_b, out);
}